// Round 13
// baseline (253.132 us; speedup 1.0000x reference)
//
#include <hip/hip_runtime.h>
#include <cstdint>
#include <cstddef>

// ---------------------------------------------------------------------------
// 2-layer GCN, round 13: eighth-wave agg (8 edges/wave-instr), 512-thread
// whole-B-LDS GEMM.
// hb layout: [4 chunks][N][32ch] bf16. k_agg: chunk=blockIdx&3 (3.2MB slab,
// XCD-affine), 8 lanes = 1 node (uint2 = 4ch each), cols in LDS, 16-deep MLP.
//   k_cvt_w: zero cursor/ovf_cnt + W1,W2 -> bf16 WT[N][K]
//   k_part / k_fill2: ELL-64 build
//   k_gemm_mfma<256,AF32>: hb = bf16((x@W1)*dinv[row]) chunk-major
//   k_agg<BF16OUT=1> -> aggbuf row-major bf16; k_gemm_mfma<128>; k_agg<0>
// ---------------------------------------------------------------------------

#define ELL_STRIDE 64
#define BCAP 8192
#define OVF_CAP 1024
#define PART_T 2048

typedef __attribute__((ext_vector_type(8))) short bf16x8;
typedef __attribute__((ext_vector_type(4))) float floatx4;

__device__ __forceinline__ unsigned short f2bf(float f) {
  unsigned int u = __float_as_uint(f);
  unsigned int r = (u + 0x7fffu + ((u >> 16) & 1u)) >> 16;   // RNE
  return (unsigned short)r;
}
__device__ __forceinline__ float2 bfpair(unsigned int p) {
  float2 r;
  r.x = __uint_as_float(p << 16);
  r.y = __uint_as_float(p & 0xffff0000u);
  return r;
}

// ---------------- zero workspace + W -> bf16 transposed [N=128][K] --------
__global__ __launch_bounds__(256) void k_cvt_w(const float* __restrict__ W1,
                                               const float* __restrict__ W2,
                                               unsigned short* __restrict__ WT1,
                                               unsigned short* __restrict__ WT2,
                                               int* __restrict__ cursor,
                                               int* __restrict__ ovf_cnt,
                                               int NB) {
  int i = blockIdx.x * 256 + threadIdx.x;
  if (i < NB) cursor[i] = 0;
  if (i == NB) *ovf_cnt = 0;
  if (i < 128 * 256) {                 // WT1[n][k] = W1[k][n], K=256
    int n = i >> 8, k = i & 255;
    WT1[i] = f2bf(W1[k * 128 + n]);
  } else if (i < 128 * 256 + 128 * 128) {
    int j = i - 128 * 256;             // WT2[n][k] = W2[k][n], K=128
    int n = j >> 7, k = j & 127;
    WT2[j] = f2bf(W2[k * 128 + n]);
  }
}

// ---------------- phase 1: bucket partition ----------------
__global__ __launch_bounds__(256) void k_part(const int* __restrict__ src,
                                              const int* __restrict__ dst,
                                              int* __restrict__ cursor,
                                              unsigned int* __restrict__ part,
                                              int* __restrict__ ovf_cnt,
                                              int* __restrict__ ovf,
                                              int E, int NB) {
  __shared__ unsigned int stage1[PART_T];
  __shared__ unsigned int stage2[PART_T];
  __shared__ int hist[512];
  __shared__ int base_g[512];
  __shared__ int base_l[512];
  __shared__ int cl[512];
  __shared__ int sc[256];
  const int tid = threadIdx.x;
  const int e0 = blockIdx.x * PART_T;
  int valid = E - e0; if (valid > PART_T) valid = PART_T;

  hist[tid] = 0; hist[tid + 256] = 0;
  cl[tid] = 0; cl[tid + 256] = 0;
  __syncthreads();
  for (int i = tid; i < valid; i += 256) {
    int e = e0 + i;
    unsigned int v = (unsigned int)(src[e] & 0xffff) | ((unsigned int)dst[e] << 16);
    stage1[i] = v;
    atomicAdd(&hist[(v >> 16) >> 7], 1);
  }
  __syncthreads();
  for (int b = tid; b < NB; b += 256) base_g[b] = atomicAdd(&cursor[b], hist[b]);
  int h0 = hist[2 * tid], h1 = hist[2 * tid + 1];
  int pv = h0 + h1;
  sc[tid] = pv;
  __syncthreads();
  #pragma unroll
  for (int off = 1; off < 256; off <<= 1) {
    int t = (tid >= off) ? sc[tid - off] : 0;
    __syncthreads();
    sc[tid] += t;
    __syncthreads();
  }
  int excl = sc[tid] - pv;
  base_l[2 * tid] = excl;
  base_l[2 * tid + 1] = excl + h0;
  __syncthreads();
  for (int i = tid; i < valid; i += 256) {
    unsigned int v = stage1[i];
    int b = (v >> 16) >> 7;
    int pos = base_l[b] + atomicAdd(&cl[b], 1);
    stage2[pos] = v;
  }
  __syncthreads();
  for (int i = tid; i < valid; i += 256) {
    unsigned int v = stage2[i];
    int b = (v >> 16) >> 7;
    int g = base_g[b] + (i - base_l[b]);
    if (g < BCAP) {
      part[(size_t)b * BCAP + g] = v;
    } else {
      int p = atomicAdd(ovf_cnt, 1);
      if (p < OVF_CAP) { ovf[2 * p] = (int)(v & 0xffffu); ovf[2 * p + 1] = (int)(v >> 16); }
    }
  }
}

// ---------------- phase 2: per-bucket ELL build in LDS ----------------
__global__ __launch_bounds__(256) void k_fill2(const unsigned int* __restrict__ part,
                                               const int* __restrict__ cursor,
                                               unsigned short* __restrict__ col,
                                               int* __restrict__ cnt,
                                               float* __restrict__ dinv,
                                               int* __restrict__ ovf_cnt,
                                               int* __restrict__ ovf, int N) {
  __shared__ unsigned short slab[128 * ELL_STRIDE];  // 16 KB
  __shared__ int cl[128];
  const int tid = threadIdx.x;
  const int b = blockIdx.x;
  if (tid < 128) cl[tid] = 0;
  __syncthreads();
  int count = cursor[b]; if (count > BCAP) count = BCAP;
  const unsigned int* p = part + (size_t)b * BCAP;
  for (int i = tid; i < count; i += 256) {
    unsigned int v = p[i];
    int row = (v >> 16) & 127;
    int k = atomicAdd(&cl[row], 1);
    if (k < ELL_STRIDE) {
      slab[row * ELL_STRIDE + k] = (unsigned short)(v & 0xffffu);
    } else {
      int q = atomicAdd(ovf_cnt, 1);
      if (q < OVF_CAP) { ovf[2 * q] = (int)(v & 0xffffu); ovf[2 * q + 1] = (int)(v >> 16); }
    }
  }
  __syncthreads();
  uint4* d4 = (uint4*)(col + (size_t)b * 128 * ELL_STRIDE);
  const uint4* s4 = (const uint4*)slab;
  #pragma unroll
  for (int i = 0; i < (128 * ELL_STRIDE * 2) / (16 * 256); ++i)
    d4[i * 256 + tid] = s4[i * 256 + tid];
  if (tid < 128) {
    int node = b * 128 + tid;
    if (node < N) {
      int c = cl[tid];
      cnt[node] = c;
      dinv[node] = rsqrtf((float)c + 1.0f);
    }
  }
}

// ---------------- MFMA GEMM -> chunk-major hb [4][M][32ch] ----------------
// 512-thread block = 8 waves x 16-row strips = 128 rows. Whole WT staged in
// LDS once (rows padded +8 shorts), single barrier, then straight MFMA.
template <int K, bool AF32>
__global__ __launch_bounds__(512) void k_gemm_mfma(const void* __restrict__ Xv,
                                                   const unsigned short* __restrict__ WT,
                                                   const float* __restrict__ dinv,
                                                   unsigned short* __restrict__ hb,
                                                   int M) {
  constexpr int KP = K + 8;
  __shared__ unsigned short Bs[128 * KP];
  const int tid = threadIdx.x;
  const int wave = tid >> 6, lane = tid & 63;
  const int q = lane >> 4, m = lane & 15;
  const int row0 = blockIdx.x * 128 + wave * 16;   // M % 16 == 0
  const bool active = row0 < M;
  const int arow = row0 + m;

  for (int c = tid; c < 128 * (K / 8); c += 512) {
    int r = c / (K / 8), ko = (c % (K / 8)) * 8;
    *(uint4*)(Bs + r * KP + ko) = *(const uint4*)(WT + (size_t)r * K + ko);
  }

  bf16x8 af[K / 32];
  if (active) {
    #pragma unroll
    for (int ks = 0; ks < K / 32; ++ks) {
      const int k0 = ks * 32 + q * 8;
      if (AF32) {
        const float* X = (const float*)Xv;
        float4 a0 = *(const float4*)(X + (size_t)arow * K + k0);
        float4 a1 = *(const float4*)(X + (size_t)arow * K + k0 + 4);
        af[ks] = (bf16x8){(short)f2bf(a0.x), (short)f2bf(a0.y),
                          (short)f2bf(a0.z), (short)f2bf(a0.w),
                          (short)f2bf(a1.x), (short)f2bf(a1.y),
                          (short)f2bf(a1.z), (short)f2bf(a1.w)};
      } else {
        af[ks] = *(const bf16x8*)((const unsigned short*)Xv +
                                  (size_t)arow * K + k0);
      }
    }
  }
  __syncthreads();
  if (!active) return;

  floatx4 acc[8];
  #pragma unroll
  for (int nt = 0; nt < 8; ++nt) acc[nt] = (floatx4){0.f, 0.f, 0.f, 0.f};
  #pragma unroll
  for (int ks = 0; ks < K / 32; ++ks) {
    const int k0 = ks * 32 + q * 8;
    #pragma unroll
    for (int nt = 0; nt < 8; ++nt) {
      bf16x8 bf = *(const bf16x8*)(Bs + (nt * 16 + m) * KP + k0);
      acc[nt] = __builtin_amdgcn_mfma_f32_16x16x32_bf16(af[ks], bf, acc[nt], 0, 0, 0);
    }
  }
  #pragma unroll
  for (int r = 0; r < 4; ++r) {
    int grow = row0 + q * 4 + r;
    float di = dinv[grow];
    #pragma unroll
    for (int nt = 0; nt < 8; ++nt)
      hb[(size_t)(nt >> 1) * M * 32 + (size_t)grow * 32 + (nt & 1) * 16 + m] =
          f2bf(acc[nt][r] * di);
  }
}

// ---------------- XCD-affine 4-chunk ELL aggregate + bias + ReLU ----------
// chunk = blockIdx&3; block = 32 nodes (4 waves x 8 eighth-nodes).
// Eighth-wave = 1 node: 8 lanes own the chunk's 8 uint2s (4ch each) ->
// each gather is dwordx2, 8 edges per wave-instr, cols from LDS, 16-deep MLP.
template <bool BF16OUT>
__global__ __launch_bounds__(256) void k_agg(const unsigned int* __restrict__ hb,
                                             const int* __restrict__ cnt,
                                             const unsigned short* __restrict__ col,
                                             const float* __restrict__ dinv,
                                             const int* __restrict__ ovf_cnt,
                                             const int* __restrict__ ovf,
                                             const float* __restrict__ bias,
                                             void* __restrict__ outv, int n) {
  __shared__ unsigned short cols[32][ELL_STRIDE];   // 4 KB
  const int tid = threadIdx.x;
  const int chunk = blockIdx.x & 3;
  const int nd0 = (blockIdx.x >> 2) * 32;
  {  // preload 32 x 64 cols: 4096 shorts = 256 threads x uint4x2
    int s = tid * 16;
    int node = nd0 + (s >> 6);
    uint4 v0 = make_uint4(0, 0, 0, 0), v1 = v0;
    if (node < n) {
      v0 = *(const uint4*)(col + (size_t)node * ELL_STRIDE + (s & 63));
      v1 = *(const uint4*)(col + (size_t)node * ELL_STRIDE + (s & 63) + 8);
    }
    *(uint4*)&cols[s >> 6][s & 63] = v0;
    *(uint4*)&cols[s >> 6][(s & 63) + 8] = v1;
  }
  __syncthreads();
  const int nodeL = tid >> 3;            // 0..31 within block
  const int d = nd0 + nodeL;
  const int w = tid & 7;                 // uint2 (4ch) within 32-ch chunk
  if (d >= n) return;
  const uint2* slab = (const uint2*)hb + (size_t)chunk * n * 8;
  const unsigned short* lc = cols[nodeL];

  // self-loop: hb pre-scaled by dinv -> hb[d]*dinv[d] = h[d]*dinv^2
  uint2 sv = slab[(size_t)d * 8 + w];
  float2 s0 = bfpair(sv.x), s1 = bfpair(sv.y);
  float a0 = s0.x, a1 = s0.y, a2 = s1.x, a3 = s1.y;

  int m = cnt[d]; if (m > ELL_STRIDE) m = ELL_STRIDE;
  int k = 0;
#define GATH(P)                                                   \
  {                                                               \
    float2 _x = bfpair((P).x), _y = bfpair((P).y);                \
    a0 += _x.x; a1 += _x.y; a2 += _y.x; a3 += _y.y;               \
  }
  for (; k + 16 <= m; k += 16) {
    ushort4 ca = *(const ushort4*)(lc + k);
    ushort4 cb = *(const ushort4*)(lc + k + 4);
    ushort4 cc = *(const ushort4*)(lc + k + 8);
    ushort4 cd = *(const ushort4*)(lc + k + 12);
    uint2 p0 = slab[(size_t)ca.x * 8 + w];
    uint2 p1 = slab[(size_t)ca.y * 8 + w];
    uint2 p2 = slab[(size_t)ca.z * 8 + w];
    uint2 p3 = slab[(size_t)ca.w * 8 + w];
    uint2 p4 = slab[(size_t)cb.x * 8 + w];
    uint2 p5 = slab[(size_t)cb.y * 8 + w];
    uint2 p6 = slab[(size_t)cb.z * 8 + w];
    uint2 p7 = slab[(size_t)cb.w * 8 + w];
    uint2 p8 = slab[(size_t)cc.x * 8 + w];
    uint2 p9 = slab[(size_t)cc.y * 8 + w];
    uint2 pa = slab[(size_t)cc.z * 8 + w];
    uint2 pb = slab[(size_t)cc.w * 8 + w];
    uint2 pc = slab[(size_t)cd.x * 8 + w];
    uint2 pd = slab[(size_t)cd.y * 8 + w];
    uint2 pe = slab[(size_t)cd.z * 8 + w];
    uint2 pf = slab[(size_t)cd.w * 8 + w];
    GATH(p0) GATH(p1) GATH(p2) GATH(p3) GATH(p4) GATH(p5) GATH(p6) GATH(p7)
    GATH(p8) GATH(p9) GATH(pa) GATH(pb) GATH(pc) GATH(pd) GATH(pe) GATH(pf)
  }
  for (; k + 8 <= m; k += 8) {
    ushort4 ca = *(const ushort4*)(lc + k);
    ushort4 cb = *(const ushort4*)(lc + k + 4);
    uint2 p0 = slab[(size_t)ca.x * 8 + w];
    uint2 p1 = slab[(size_t)ca.y * 8 + w];
    uint2 p2 = slab[(size_t)ca.z * 8 + w];
    uint2 p3 = slab[(size_t)ca.w * 8 + w];
    uint2 p4 = slab[(size_t)cb.x * 8 + w];
    uint2 p5 = slab[(size_t)cb.y * 8 + w];
    uint2 p6 = slab[(size_t)cb.z * 8 + w];
    uint2 p7 = slab[(size_t)cb.w * 8 + w];
    GATH(p0) GATH(p1) GATH(p2) GATH(p3) GATH(p4) GATH(p5) GATH(p6) GATH(p7)
  }
  for (; k < m; ++k) {
    uint2 p = slab[(size_t)lc[k] * 8 + w];
    GATH(p)
  }
  int V = *ovf_cnt; if (V > OVF_CAP) V = OVF_CAP;
  for (int j = 0; j < V; ++j) {
    if (ovf[2 * j + 1] == d) {
      uint2 p = slab[(size_t)ovf[2 * j] * 8 + w];
      GATH(p)
    }
  }
#undef GATH
  float di = dinv[d];
  float4 bv = *(const float4*)(bias + chunk * 32 + w * 4);
  float r0 = fmaxf(di * a0 + bv.x, 0.f);
  float r1 = fmaxf(di * a1 + bv.y, 0.f);
  float r2 = fmaxf(di * a2 + bv.z, 0.f);
  float r3 = fmaxf(di * a3 + bv.w, 0.f);
  if (BF16OUT) {   // row-major [N][128] bf16 (true channel order) for gemm2
    uint2 pk;
    pk.x = (unsigned int)f2bf(r0) | ((unsigned int)f2bf(r1) << 16);
    pk.y = (unsigned int)f2bf(r2) | ((unsigned int)f2bf(r3) << 16);
    ((uint2*)outv)[(size_t)d * 32 + chunk * 8 + w] = pk;
  } else {
    *(float4*)((float*)outv + (size_t)d * 128 + chunk * 32 + w * 4) =
        make_float4(r0, r1, r2, r3);
  }
}

// ---------------------------------------------------------------------------
extern "C" void kernel_launch(void* const* d_in, const int* in_sizes, int n_in,
                              void* d_out, int out_size, void* d_ws, size_t ws_size,
                              hipStream_t stream) {
  const float* x  = (const float*)d_in[0];
  const int*   ei = (const int*)d_in[1];
  const float* W1 = (const float*)d_in[2];
  const float* b1 = (const float*)d_in[3];
  const float* W2 = (const float*)d_in[4];
  const float* b2 = (const float*)d_in[5];
  float* out = (float*)d_out;

  const int IN_CH = 256;
  const int N = in_sizes[0] / IN_CH;   // 50000
  const int E = in_sizes[1] / 2;       // 1,600,000
  const int NB = (N + 127) >> 7;       // 391 buckets

  const int* src = ei;
  const int* dst = ei + E;

  char* ws = (char*)d_ws;
  size_t off = 0;
  auto carve = [&](size_t bytes) {
    void* p = ws + off;
    off += (bytes + 255) & ~(size_t)255;
    return p;
  };
  int*            cursor  = (int*)carve((size_t)NB * 4);
  int*            ovf_cnt = (int*)carve(4);
  int*            ovf     = (int*)carve((size_t)OVF_CAP * 2 * 4);
  int*            cnt     = (int*)carve((size_t)N * 4);
  float*          dinv    = (float*)carve((size_t)N * 4);
  unsigned short* col     = (unsigned short*)carve((size_t)N * ELL_STRIDE * 2); // 6.4MB
  unsigned short* hb      = (unsigned short*)carve((size_t)N * 128 * 2);        // [4][N][32] 12.8MB
  unsigned short* WT1     = (unsigned short*)carve(128 * 256 * 2);
  unsigned short* WT2     = (unsigned short*)carve(128 * 128 * 2);
  // union: part (dead after k_fill2) aliases aggbuf (bf16, by k_agg#1)
  char*           unionp  = (char*)carve((size_t)NB * BCAP * 4);   // 12.8MB
  unsigned int*   part    = (unsigned int*)unionp;
  unsigned short* aggbuf  = (unsigned short*)unionp;               // [N][128] bf16

  k_cvt_w<<<(128 * 256 + 128 * 128 + 255) / 256, 256, 0, stream>>>(
      W1, W2, WT1, WT2, cursor, ovf_cnt, NB);
  k_part <<<(E + PART_T - 1) / PART_T, 256, 0, stream>>>(src, dst, cursor, part,
                                                         ovf_cnt, ovf, E, NB);
  k_fill2<<<NB, 256, 0, stream>>>(part, cursor, col, cnt, dinv, ovf_cnt, ovf, N);

  int gblocks = (N + 127) / 128;         // 391
  int ablocks = 4 * ((N + 31) / 32);     // 4 chunks x 1563
  k_gemm_mfma<256, true ><<<gblocks, 512, 0, stream>>>(x, WT1, dinv, hb, N);
  k_agg<true ><<<ablocks, 256, 0, stream>>>((const unsigned int*)hb, cnt, col, dinv,
                                            ovf_cnt, ovf, b1, aggbuf, N);
  k_gemm_mfma<128, false><<<gblocks, 512, 0, stream>>>(aggbuf, WT2, dinv, hb, N);
  k_agg<false><<<ablocks, 256, 0, stream>>>((const unsigned int*)hb, cnt, col, dinv,
                                            ovf_cnt, ovf, b2, out, N);
}

// Round 14
// 235.589 us; speedup vs baseline: 1.0745x; 1.0745x over previous
//
#include <hip/hip_runtime.h>
#include <cstdint>
#include <cstddef>

// ---------------------------------------------------------------------------
// 2-layer GCN, round 14: quarter-group agg (16 edges/VMEM-instr, dwordx4
// gathers), dummy-node padding (no guards), 72-short padded LDS cols.
// hb layout: [4 chunks][N+1][32ch] bf16; row N of each chunk is zero (dummy).
//   k_cvt_w: zero cursor/ovf_cnt + dummy hb rows + W1,W2 -> bf16 WT[N][K]
//   k_part / k_fill2: ELL-64 build (fill2 inits slab to dummy index N)
//   k_gemm_mfma<256,AF32>: hb = bf16((x@W1)*dinv[row]) chunk-major
//   k_agg<BF16OUT=1> -> aggbuf row-major bf16; k_gemm_mfma<128>; k_agg<0>
// ---------------------------------------------------------------------------

#define ELL_STRIDE 64
#define BCAP 8192
#define OVF_CAP 1024
#define PART_T 2048

typedef __attribute__((ext_vector_type(8))) short bf16x8;
typedef __attribute__((ext_vector_type(4))) float floatx4;

__device__ __forceinline__ unsigned short f2bf(float f) {
  unsigned int u = __float_as_uint(f);
  unsigned int r = (u + 0x7fffu + ((u >> 16) & 1u)) >> 16;   // RNE
  return (unsigned short)r;
}
__device__ __forceinline__ float2 bfpair(unsigned int p) {
  float2 r;
  r.x = __uint_as_float(p << 16);
  r.y = __uint_as_float(p & 0xffff0000u);
  return r;
}

// -------- zero workspace + dummy hb rows + W -> bf16 transposed [128][K] ---
__global__ __launch_bounds__(256) void k_cvt_w(const float* __restrict__ W1,
                                               const float* __restrict__ W2,
                                               unsigned short* __restrict__ WT1,
                                               unsigned short* __restrict__ WT2,
                                               int* __restrict__ cursor,
                                               int* __restrict__ ovf_cnt,
                                               unsigned short* __restrict__ hb,
                                               int N, int NB) {
  int i = blockIdx.x * 256 + threadIdx.x;
  if (i < NB) cursor[i] = 0;
  if (i == NB) *ovf_cnt = 0;
  if (i < 128) {   // zero dummy row N of each chunk: 4 x 32 shorts
    int chunk = i >> 5, j = i & 31;
    hb[(size_t)chunk * (N + 1) * 32 + (size_t)N * 32 + j] = 0;
  }
  if (i < 128 * 256) {                 // WT1[n][k] = W1[k][n], K=256
    int n = i >> 8, k = i & 255;
    WT1[i] = f2bf(W1[k * 128 + n]);
  } else if (i < 128 * 256 + 128 * 128) {
    int j = i - 128 * 256;             // WT2[n][k] = W2[k][n], K=128
    int n = j >> 7, k = j & 127;
    WT2[j] = f2bf(W2[k * 128 + n]);
  }
}

// ---------------- phase 1: bucket partition ----------------
__global__ __launch_bounds__(256) void k_part(const int* __restrict__ src,
                                              const int* __restrict__ dst,
                                              int* __restrict__ cursor,
                                              unsigned int* __restrict__ part,
                                              int* __restrict__ ovf_cnt,
                                              int* __restrict__ ovf,
                                              int E, int NB) {
  __shared__ unsigned int stage1[PART_T];
  __shared__ unsigned int stage2[PART_T];
  __shared__ int hist[512];
  __shared__ int base_g[512];
  __shared__ int base_l[512];
  __shared__ int cl[512];
  __shared__ int sc[256];
  const int tid = threadIdx.x;
  const int e0 = blockIdx.x * PART_T;
  int valid = E - e0; if (valid > PART_T) valid = PART_T;

  hist[tid] = 0; hist[tid + 256] = 0;
  cl[tid] = 0; cl[tid + 256] = 0;
  __syncthreads();
  for (int i = tid; i < valid; i += 256) {
    int e = e0 + i;
    unsigned int v = (unsigned int)(src[e] & 0xffff) | ((unsigned int)dst[e] << 16);
    stage1[i] = v;
    atomicAdd(&hist[(v >> 16) >> 7], 1);
  }
  __syncthreads();
  for (int b = tid; b < NB; b += 256) base_g[b] = atomicAdd(&cursor[b], hist[b]);
  int h0 = hist[2 * tid], h1 = hist[2 * tid + 1];
  int pv = h0 + h1;
  sc[tid] = pv;
  __syncthreads();
  #pragma unroll
  for (int off = 1; off < 256; off <<= 1) {
    int t = (tid >= off) ? sc[tid - off] : 0;
    __syncthreads();
    sc[tid] += t;
    __syncthreads();
  }
  int excl = sc[tid] - pv;
  base_l[2 * tid] = excl;
  base_l[2 * tid + 1] = excl + h0;
  __syncthreads();
  for (int i = tid; i < valid; i += 256) {
    unsigned int v = stage1[i];
    int b = (v >> 16) >> 7;
    int pos = base_l[b] + atomicAdd(&cl[b], 1);
    stage2[pos] = v;
  }
  __syncthreads();
  for (int i = tid; i < valid; i += 256) {
    unsigned int v = stage2[i];
    int b = (v >> 16) >> 7;
    int g = base_g[b] + (i - base_l[b]);
    if (g < BCAP) {
      part[(size_t)b * BCAP + g] = v;
    } else {
      int p = atomicAdd(ovf_cnt, 1);
      if (p < OVF_CAP) { ovf[2 * p] = (int)(v & 0xffffu); ovf[2 * p + 1] = (int)(v >> 16); }
    }
  }
}

// ---------------- phase 2: per-bucket ELL build in LDS ----------------
// slab pre-initialized to dummy index N -> unfilled slots gather a zero row.
__global__ __launch_bounds__(256) void k_fill2(const unsigned int* __restrict__ part,
                                               const int* __restrict__ cursor,
                                               unsigned short* __restrict__ col,
                                               int* __restrict__ cnt,
                                               float* __restrict__ dinv,
                                               int* __restrict__ ovf_cnt,
                                               int* __restrict__ ovf, int N) {
  __shared__ unsigned short slab[128 * ELL_STRIDE];  // 16 KB
  __shared__ int cl[128];
  const int tid = threadIdx.x;
  const int b = blockIdx.x;
  if (tid < 128) cl[tid] = 0;
  {
    unsigned int dpk = ((unsigned int)N << 16) | (unsigned int)N;
    unsigned int* s32 = (unsigned int*)slab;
    #pragma unroll
    for (int i = 0; i < (128 * ELL_STRIDE / 2) / 256; ++i)
      s32[i * 256 + tid] = dpk;
  }
  __syncthreads();
  int count = cursor[b]; if (count > BCAP) count = BCAP;
  const unsigned int* p = part + (size_t)b * BCAP;
  for (int i = tid; i < count; i += 256) {
    unsigned int v = p[i];
    int row = (v >> 16) & 127;
    int k = atomicAdd(&cl[row], 1);
    if (k < ELL_STRIDE) {
      slab[row * ELL_STRIDE + k] = (unsigned short)(v & 0xffffu);
    } else {
      int q = atomicAdd(ovf_cnt, 1);
      if (q < OVF_CAP) { ovf[2 * q] = (int)(v & 0xffffu); ovf[2 * q + 1] = (int)(v >> 16); }
    }
  }
  __syncthreads();
  uint4* d4 = (uint4*)(col + (size_t)b * 128 * ELL_STRIDE);
  const uint4* s4 = (const uint4*)slab;
  #pragma unroll
  for (int i = 0; i < (128 * ELL_STRIDE * 2) / (16 * 256); ++i)
    d4[i * 256 + tid] = s4[i * 256 + tid];
  if (tid < 128) {
    int node = b * 128 + tid;
    if (node < N) {
      int c = cl[tid];
      cnt[node] = c;
      dinv[node] = rsqrtf((float)c + 1.0f);
    }
  }
}

// ---------------- MFMA GEMM -> chunk-major hb [4][M+1][32ch] --------------
// 512-thread block = 8 waves x 16-row strips = 128 rows. Whole WT staged in
// LDS once (rows padded +8 shorts), single barrier, then straight MFMA.
template <int K, bool AF32>
__global__ __launch_bounds__(512) void k_gemm_mfma(const void* __restrict__ Xv,
                                                   const unsigned short* __restrict__ WT,
                                                   const float* __restrict__ dinv,
                                                   unsigned short* __restrict__ hb,
                                                   int M) {
  constexpr int KP = K + 8;
  __shared__ unsigned short Bs[128 * KP];
  const int tid = threadIdx.x;
  const int wave = tid >> 6, lane = tid & 63;
  const int q = lane >> 4, m = lane & 15;
  const int row0 = blockIdx.x * 128 + wave * 16;   // M % 16 == 0
  const bool active = row0 < M;
  const int arow = row0 + m;

  for (int c = tid; c < 128 * (K / 8); c += 512) {
    int r = c / (K / 8), ko = (c % (K / 8)) * 8;
    *(uint4*)(Bs + r * KP + ko) = *(const uint4*)(WT + (size_t)r * K + ko);
  }

  bf16x8 af[K / 32];
  if (active) {
    #pragma unroll
    for (int ks = 0; ks < K / 32; ++ks) {
      const int k0 = ks * 32 + q * 8;
      if (AF32) {
        const float* X = (const float*)Xv;
        float4 a0 = *(const float4*)(X + (size_t)arow * K + k0);
        float4 a1 = *(const float4*)(X + (size_t)arow * K + k0 + 4);
        af[ks] = (bf16x8){(short)f2bf(a0.x), (short)f2bf(a0.y),
                          (short)f2bf(a0.z), (short)f2bf(a0.w),
                          (short)f2bf(a1.x), (short)f2bf(a1.y),
                          (short)f2bf(a1.z), (short)f2bf(a1.w)};
      } else {
        af[ks] = *(const bf16x8*)((const unsigned short*)Xv +
                                  (size_t)arow * K + k0);
      }
    }
  }
  __syncthreads();
  if (!active) return;

  floatx4 acc[8];
  #pragma unroll
  for (int nt = 0; nt < 8; ++nt) acc[nt] = (floatx4){0.f, 0.f, 0.f, 0.f};
  #pragma unroll
  for (int ks = 0; ks < K / 32; ++ks) {
    const int k0 = ks * 32 + q * 8;
    #pragma unroll
    for (int nt = 0; nt < 8; ++nt) {
      bf16x8 bf = *(const bf16x8*)(Bs + (nt * 16 + m) * KP + k0);
      acc[nt] = __builtin_amdgcn_mfma_f32_16x16x32_bf16(af[ks], bf, acc[nt], 0, 0, 0);
    }
  }
  #pragma unroll
  for (int r = 0; r < 4; ++r) {
    int grow = row0 + q * 4 + r;
    float di = dinv[grow];
    #pragma unroll
    for (int nt = 0; nt < 8; ++nt)
      hb[(size_t)(nt >> 1) * (M + 1) * 32 + (size_t)grow * 32 + (nt & 1) * 16 + m] =
          f2bf(acc[nt][r] * di);
  }
}

// ---------------- XCD-affine 4-chunk ELL aggregate + bias + ReLU ----------
// chunk = blockIdx&3; block = 64 nodes (4 waves x 16 quarter-group nodes).
// Quarter-group = 1 node: 4 lanes x dwordx4 cover the 64B chunk row ->
// one VMEM instr gathers 16 edges. Cols in LDS (72-short padded rows,
// 2-way bank alias only). No guards: ELL slots >= deg hold dummy node N
// whose hb row is zero.
template <bool BF16OUT>
__global__ __launch_bounds__(256) void k_agg(const uint4* __restrict__ hb4,
                                             const int* __restrict__ cnt,
                                             const unsigned short* __restrict__ col,
                                             const float* __restrict__ dinv,
                                             const int* __restrict__ ovf_cnt,
                                             const int* __restrict__ ovf,
                                             const float* __restrict__ bias,
                                             void* __restrict__ outv, int n) {
  __shared__ unsigned short cols[64][72];   // padded: bank spread {0,4,..,60}
  const int tid = threadIdx.x;
  const int chunk = blockIdx.x & 3;
  const int nd0 = (blockIdx.x >> 2) * 64;
  {  // preload 64 x 64 cols (dummy-filled for OOB nodes)
    unsigned int dpk = ((unsigned int)n << 16) | (unsigned int)n;
    int s = tid * 16;                       // 256 x 16 = 4096 shorts
    int node = s >> 6, off = s & 63;
    uint4 v0 = make_uint4(dpk, dpk, dpk, dpk), v1 = v0;
    if (nd0 + node < n) {
      v0 = *(const uint4*)(col + (size_t)(nd0 + node) * ELL_STRIDE + off);
      v1 = *(const uint4*)(col + (size_t)(nd0 + node) * ELL_STRIDE + off + 8);
    }
    *(uint4*)&cols[node][off] = v0;
    *(uint4*)&cols[node][off + 8] = v1;
  }
  __syncthreads();
  const int wave = tid >> 6, lane = tid & 63;
  const int nodeL = wave * 16 + (lane >> 2);
  const int q = lane & 3;                   // uint4 (8ch) within 32-ch chunk
  const int d = nd0 + nodeL;
  const bool valid = d < n;
  const uint4* slab = hb4 + (size_t)chunk * (n + 1) * 4;
  const unsigned short* lc = cols[nodeL];

  float a0 = 0.f, a1 = 0.f, a2 = 0.f, a3 = 0.f;
  float a4 = 0.f, a5 = 0.f, a6 = 0.f, a7 = 0.f;
#define ADDP(P)                                                            \
  {                                                                        \
    float2 x0 = bfpair((P).x), x1 = bfpair((P).y);                         \
    float2 x2 = bfpair((P).z), x3 = bfpair((P).w);                         \
    a0 += x0.x; a1 += x0.y; a2 += x1.x; a3 += x1.y;                        \
    a4 += x2.x; a5 += x2.y; a6 += x3.x; a7 += x3.y;                        \
  }
  if (valid) {   // self-loop: hb pre-scaled by dinv -> hb[d]*dinv[d]
    uint4 p = slab[(size_t)d * 4 + q];
    ADDP(p)
  }
  int m = valid ? cnt[d] : 0; if (m > ELL_STRIDE) m = ELL_STRIDE;
  int mmax = m;
  #pragma unroll
  for (int s = 4; s < 64; s <<= 1) {
    int o = __shfl_xor(mmax, s);
    mmax = o > mmax ? o : mmax;
  }
  for (int k = 0; k < mmax; k += 8) {
    ushort4 ca = *(const ushort4*)(lc + k);
    ushort4 cb = *(const ushort4*)(lc + k + 4);
    uint4 p0 = slab[(size_t)ca.x * 4 + q];
    uint4 p1 = slab[(size_t)ca.y * 4 + q];
    uint4 p2 = slab[(size_t)ca.z * 4 + q];
    uint4 p3 = slab[(size_t)ca.w * 4 + q];
    uint4 p4 = slab[(size_t)cb.x * 4 + q];
    uint4 p5 = slab[(size_t)cb.y * 4 + q];
    uint4 p6 = slab[(size_t)cb.z * 4 + q];
    uint4 p7 = slab[(size_t)cb.w * 4 + q];
    ADDP(p0) ADDP(p1) ADDP(p2) ADDP(p3)
    ADDP(p4) ADDP(p5) ADDP(p6) ADDP(p7)
  }
  if (valid) {
    int V = *ovf_cnt; if (V > OVF_CAP) V = OVF_CAP;
    for (int j = 0; j < V; ++j) {
      if (ovf[2 * j + 1] == d) {
        uint4 p = slab[(size_t)ovf[2 * j] * 4 + q];
        ADDP(p)
      }
    }
  }
#undef ADDP
  if (!valid) return;
  float di = dinv[d];
  float4 b0 = *(const float4*)(bias + chunk * 32 + q * 8);
  float4 b1 = *(const float4*)(bias + chunk * 32 + q * 8 + 4);
  float r0 = fmaxf(di * a0 + b0.x, 0.f);
  float r1 = fmaxf(di * a1 + b0.y, 0.f);
  float r2 = fmaxf(di * a2 + b0.z, 0.f);
  float r3 = fmaxf(di * a3 + b0.w, 0.f);
  float r4 = fmaxf(di * a4 + b1.x, 0.f);
  float r5 = fmaxf(di * a5 + b1.y, 0.f);
  float r6 = fmaxf(di * a6 + b1.z, 0.f);
  float r7 = fmaxf(di * a7 + b1.w, 0.f);
  if (BF16OUT) {   // row-major [N][128] bf16 (true channel order) for gemm2
    uint4 pk;
    pk.x = (unsigned int)f2bf(r0) | ((unsigned int)f2bf(r1) << 16);
    pk.y = (unsigned int)f2bf(r2) | ((unsigned int)f2bf(r3) << 16);
    pk.z = (unsigned int)f2bf(r4) | ((unsigned int)f2bf(r5) << 16);
    pk.w = (unsigned int)f2bf(r6) | ((unsigned int)f2bf(r7) << 16);
    ((uint4*)outv)[(size_t)d * 16 + chunk * 4 + q] = pk;
  } else {
    float* o = (float*)outv + (size_t)d * 128 + chunk * 32 + q * 8;
    *(float4*)o = make_float4(r0, r1, r2, r3);
    *(float4*)(o + 4) = make_float4(r4, r5, r6, r7);
  }
}

// ---------------------------------------------------------------------------
extern "C" void kernel_launch(void* const* d_in, const int* in_sizes, int n_in,
                              void* d_out, int out_size, void* d_ws, size_t ws_size,
                              hipStream_t stream) {
  const float* x  = (const float*)d_in[0];
  const int*   ei = (const int*)d_in[1];
  const float* W1 = (const float*)d_in[2];
  const float* b1 = (const float*)d_in[3];
  const float* W2 = (const float*)d_in[4];
  const float* b2 = (const float*)d_in[5];
  float* out = (float*)d_out;

  const int IN_CH = 256;
  const int N = in_sizes[0] / IN_CH;   // 50000
  const int E = in_sizes[1] / 2;       // 1,600,000
  const int NB = (N + 127) >> 7;       // 391 buckets

  const int* src = ei;
  const int* dst = ei + E;

  char* ws = (char*)d_ws;
  size_t off = 0;
  auto carve = [&](size_t bytes) {
    void* p = ws + off;
    off += (bytes + 255) & ~(size_t)255;
    return p;
  };
  int*            cursor  = (int*)carve((size_t)NB * 4);
  int*            ovf_cnt = (int*)carve(4);
  int*            ovf     = (int*)carve((size_t)OVF_CAP * 2 * 4);
  int*            cnt     = (int*)carve((size_t)N * 4);
  float*          dinv    = (float*)carve((size_t)N * 4);
  unsigned short* col     = (unsigned short*)carve((size_t)N * ELL_STRIDE * 2); // 6.4MB
  unsigned short* hb      = (unsigned short*)carve((size_t)(N + 1) * 256);      // [4][N+1][32]
  unsigned short* WT1     = (unsigned short*)carve(128 * 256 * 2);
  unsigned short* WT2     = (unsigned short*)carve(128 * 128 * 2);
  // union: part (dead after k_fill2) aliases aggbuf (bf16, by k_agg#1)
  char*           unionp  = (char*)carve((size_t)NB * BCAP * 4);   // 12.8MB
  unsigned int*   part    = (unsigned int*)unionp;
  unsigned short* aggbuf  = (unsigned short*)unionp;               // [N][128] bf16

  k_cvt_w<<<(128 * 256 + 128 * 128 + 255) / 256, 256, 0, stream>>>(
      W1, W2, WT1, WT2, cursor, ovf_cnt, hb, N, NB);
  k_part <<<(E + PART_T - 1) / PART_T, 256, 0, stream>>>(src, dst, cursor, part,
                                                         ovf_cnt, ovf, E, NB);
  k_fill2<<<NB, 256, 0, stream>>>(part, cursor, col, cnt, dinv, ovf_cnt, ovf, N);

  int gblocks = (N + 127) / 128;         // 391
  int ablocks = 4 * ((N + 63) / 64);     // 4 chunks x 782
  k_gemm_mfma<256, true ><<<gblocks, 512, 0, stream>>>(x, WT1, dinv, hb, N);
  k_agg<true ><<<ablocks, 256, 0, stream>>>((const uint4*)hb, cnt, col, dinv,
                                            ovf_cnt, ovf, b1, aggbuf, N);
  k_gemm_mfma<128, false><<<gblocks, 512, 0, stream>>>(aggbuf, WT2, dinv, hb, N);
  k_agg<false><<<ablocks, 256, 0, stream>>>((const uint4*)hb, cnt, col, dinv,
                                            ovf_cnt, ovf, b2, out, N);
}